// Round 1
// baseline (10524.094 us; speedup 1.0000x reference)
//
#include <hip/hip_runtime.h>
#include <hip/hip_bf16.h>
#include <math.h>

// CWVAE RSSM on MI355X. Levels L=3 run top-down; each level scans T steps.
// Dead code removed: prior head (w2,b2,wpm,bpm,wps,bps) and np* noises are
// unused by the reference output (only q_sample ++ det_new is returned).

#define LVLS 3
#define FACT 6
#define NB 64
#define TT0 36
#define NE 1024
#define NS 128
#define ND 1024
#define NH 1024
#define NO (NS + ND)  // 1152

typedef __attribute__((ext_vector_type(8))) short bf16x8;
typedef __attribute__((ext_vector_type(4))) float f32x4;
typedef unsigned short u16;

#define MFMA(a, b, c) __builtin_amdgcn_mfma_f32_16x16x32_bf16(a, b, c, 0, 0, 0)

__device__ inline u16 f2bf(float x) {
    unsigned u = __float_as_uint(x);
    unsigned r = u + 0x7fffu + ((u >> 16) & 1u);  // RNE
    return (u16)(r >> 16);
}

// A-fragment for mfma_f32_16x16x32_bf16: lane l -> row = l&15, k = (l>>4)*8 + e
__device__ inline bf16x8 load_a(const float* __restrict__ base, int ld, int lane, int k0) {
    const float* p = base + (size_t)(lane & 15) * ld + k0 + ((lane >> 4) << 3);
    float4 u0 = ((const float4*)p)[0];
    float4 u1 = ((const float4*)p)[1];
    bf16x8 f;
    f[0] = (short)f2bf(u0.x); f[1] = (short)f2bf(u0.y);
    f[2] = (short)f2bf(u0.z); f[3] = (short)f2bf(u0.w);
    f[4] = (short)f2bf(u1.x); f[5] = (short)f2bf(u1.y);
    f[6] = (short)f2bf(u1.z); f[7] = (short)f2bf(u1.w);
    return f;
}

// Pack fp32 weight [K,N] row-major -> bf16 fragment layout [N/16][K/32][64 lanes][8]
// frag(lane,e) = W[kt*32 + (lane>>4)*8 + e][nt*16 + (lane&15)]
__global__ __launch_bounds__(256) void k_pack(const float* __restrict__ src, int K, int N,
                                              u16* __restrict__ dst) {
    int i = blockIdx.x * blockDim.x + threadIdx.x;
    int KT = K >> 5;
    int total = (N >> 4) * KT * 64;
    if (i >= total) return;
    int lane = i & 63;
    int t = i >> 6;
    int kt = t % KT, nt = t / KT;
    int n = (nt << 4) + (lane & 15);
    int k = (kt << 5) + ((lane >> 4) << 3);
    const float* p = src + (size_t)k * N + n;
    bf16x8 v;
#pragma unroll
    for (int e = 0; e < 8; ++e) v[e] = (short)f2bf(p[(size_t)e * N]);
    reinterpret_cast<bf16x8*>(dst)[i] = v;
}

// out[64][1024] = elu(A1[64][K1] @ W[0:K1] + A2[64][K2] @ W[K1:K1+K2] + bias)
// A2 may be null (treated as zeros). Grid: 16 blocks x 256 thr (4 waves, 16 rows each).
template <int KT1, int KT2>
__global__ __launch_bounds__(256) void k_dense(const float* __restrict__ A1, int ld1,
                                               const float* __restrict__ A2, int ld2,
                                               const bf16x8* __restrict__ P,
                                               const float* __restrict__ bias,
                                               float* __restrict__ out) {
    constexpr int KT = KT1 + KT2;
    int lane = threadIdx.x & 63, wave = threadIdx.x >> 6;
    int c0 = blockIdx.x * 64;
    f32x4 acc[4] = {};
    const float* a1 = A1 + (size_t)(wave * 16) * ld1;
    for (int kt = 0; kt < KT1; ++kt) {
        bf16x8 a = load_a(a1, ld1, lane, kt * 32);
#pragma unroll
        for (int nt = 0; nt < 4; ++nt)
            acc[nt] = MFMA(a, P[((size_t)((c0 >> 4) + nt) * KT + kt) * 64 + lane], acc[nt]);
    }
    if constexpr (KT2 > 0) {
        if (A2) {
            const float* a2 = A2 + (size_t)(wave * 16) * ld2;
            for (int kt = 0; kt < KT2; ++kt) {
                bf16x8 a = load_a(a2, ld2, lane, kt * 32);
#pragma unroll
                for (int nt = 0; nt < 4; ++nt)
                    acc[nt] = MFMA(a, P[((size_t)((c0 >> 4) + nt) * KT + KT1 + kt) * 64 + lane],
                                   acc[nt]);
            }
        }
    }
    int colb = c0 + (lane & 15);
    int row0 = wave * 16 + ((lane >> 4) << 2);
#pragma unroll
    for (int nt = 0; nt < 4; ++nt) {
        int col = colb + nt * 16;
        float bv = bias[col];
#pragma unroll
        for (int j = 0; j < 4; ++j) {
            float x = acc[nt][j] + bv;
            out[(size_t)(row0 + j) * 1024 + col] = x > 0.f ? x : expm1f(x);
        }
    }
}

// Fused GRU: gi = h@Wi, gh = det@Wh (3 gates each), gates + state update.
// Grid: 32 blocks x 256 thr; block covers 32 cols of D, all 64 rows.
__global__ __launch_bounds__(256) void k_gru(const float* __restrict__ h,
                                             const float* __restrict__ det_in,
                                             const bf16x8* __restrict__ Pgi,
                                             const bf16x8* __restrict__ Pgh,
                                             const float* __restrict__ gbi,
                                             const float* __restrict__ gbh,
                                             float* __restrict__ det_out) {
    int lane = threadIdx.x & 63, wave = threadIdx.x >> 6;
    int c0 = blockIdx.x * 32;
    const int KT = 32;  // 1024/32
    f32x4 ai[3][2] = {}, ah[3][2] = {};
    const float* Ah = h + (size_t)(wave * 16) * NH;
    const float* Ad = det_in + (size_t)(wave * 16) * ND;
    for (int kt = 0; kt < 32; ++kt) {
        bf16x8 a1 = load_a(Ah, NH, lane, kt * 32);
        bf16x8 a2 = load_a(Ad, ND, lane, kt * 32);
#pragma unroll
        for (int g = 0; g < 3; ++g) {
#pragma unroll
            for (int nt = 0; nt < 2; ++nt) {
                int ntg = ((g * ND + c0) >> 4) + nt;  // pack over N=3072
                ai[g][nt] = MFMA(a1, Pgi[((size_t)ntg * KT + kt) * 64 + lane], ai[g][nt]);
                ah[g][nt] = MFMA(a2, Pgh[((size_t)ntg * KT + kt) * 64 + lane], ah[g][nt]);
            }
        }
    }
    int colb = c0 + (lane & 15);
    int row0 = wave * 16 + ((lane >> 4) << 2);
#pragma unroll
    for (int nt = 0; nt < 2; ++nt) {
        int col = colb + nt * 16;
        float bir = gbi[col], biz = gbi[ND + col], bin = gbi[2 * ND + col];
        float bhr = gbh[col], bhz = gbh[ND + col], bhn = gbh[2 * ND + col];
#pragma unroll
        for (int j = 0; j < 4; ++j) {
            int row = row0 + j;
            float r = 1.f / (1.f + expf(-(ai[0][nt][j] + bir + ah[0][nt][j] + bhr)));
            float z = 1.f / (1.f + expf(-(ai[1][nt][j] + biz + ah[1][nt][j] + bhz)));
            float n = tanhf(ai[2][nt][j] + bin + r * (ah[2][nt][j] + bhn));
            float dv = det_in[(size_t)row * ND + col];
            det_out[(size_t)row * ND + col] = (1.f - z) * n + z * dv;
        }
    }
}

// Heads + output write. Blocks 0..1: q_sample (mean + softplus-std * eps) for 64 cols each,
// writes sample_out and out[:,t,0:128]. Blocks 2..17: copy det -> out[:,t,128:1152].
__global__ __launch_bounds__(256) void k_out(const float* __restrict__ hq2,
                                             const float* __restrict__ det,
                                             const bf16x8* __restrict__ Pqh,
                                             const float* __restrict__ bqm,
                                             const float* __restrict__ bqs,
                                             const float* __restrict__ nq, int nq_stride,
                                             float* __restrict__ sample_out,
                                             float* __restrict__ outp, int out_stride) {
    int blk = blockIdx.x;
    if (blk >= 2) {
        int i = (blk - 2) * 256 + threadIdx.x;  // 4096 threads, 4 float4 each
#pragma unroll
        for (int it = 0; it < 4; ++it) {
            int idx = i + it * 4096;  // over 16384 float4 (64 x 1024 floats)
            int row = idx >> 8;
            int c4 = idx & 255;
            float4 v = ((const float4*)det)[idx];
            *(float4*)(outp + (size_t)row * out_stride + 128 + c4 * 4) = v;
        }
        return;
    }
    int lane = threadIdx.x & 63, wave = threadIdx.x >> 6;
    int c0 = blk * 64;
    const int KT = 32;
    f32x4 am[4] = {}, as_[4] = {};
    const float* A = hq2 + (size_t)(wave * 16) * NH;
    for (int kt = 0; kt < 32; ++kt) {
        bf16x8 a = load_a(A, NH, lane, kt * 32);
#pragma unroll
        for (int nt = 0; nt < 4; ++nt) {
            int ntm = (c0 >> 4) + nt;
            int nts = 8 + ntm;
            am[nt] = MFMA(a, Pqh[((size_t)ntm * KT + kt) * 64 + lane], am[nt]);
            as_[nt] = MFMA(a, Pqh[((size_t)nts * KT + kt) * 64 + lane], as_[nt]);
        }
    }
    int colb = c0 + (lane & 15);
    int row0 = wave * 16 + ((lane >> 4) << 2);
#pragma unroll
    for (int nt = 0; nt < 4; ++nt) {
        int col = colb + nt * 16;
        float bm = bqm[col], bs = bqs[col];
#pragma unroll
        for (int j = 0; j < 4; ++j) {
            int row = row0 + j;
            float mean = am[nt][j] + bm;
            float xs = as_[nt][j] + bs;
            float sp = fmaxf(xs, 0.f) + log1pf(expf(-fabsf(xs)));  // stable softplus
            float sd = sp + 1e-4f;
            float q = mean + sd * nq[(size_t)row * nq_stride + col];
            sample_out[(size_t)row * NS + col] = q;
            outp[(size_t)row * out_stride + col] = q;
        }
    }
}

extern "C" void kernel_launch(void* const* d_in, const int* in_sizes, int n_in,
                              void* d_out, int out_size, void* d_ws, size_t ws_size,
                              hipStream_t stream) {
    (void)n_in; (void)out_size; (void)ws_size;
    // Input order: dict order (x0,np0,nq0,x1,...) vs reference-signature order
    // (x0,x1,x2,np0,...). Detect via in_sizes[1].
    int ix[3], inq[3];
    if (in_sizes[1] == NB * TT0 * NS) {  // dict order: [1] = np0
        ix[0] = 0; inq[0] = 2; ix[1] = 3; inq[1] = 5; ix[2] = 6; inq[2] = 8;
    } else {                             // signature order
        ix[0] = 0; ix[1] = 1; ix[2] = 2; inq[0] = 6; inq[1] = 7; inq[2] = 8;
    }
    const float* x[3]  = {(const float*)d_in[ix[0]], (const float*)d_in[ix[1]], (const float*)d_in[ix[2]]};
    const float* nqp[3] = {(const float*)d_in[inq[0]], (const float*)d_in[inq[1]], (const float*)d_in[inq[2]]};
    const float* w1w = (const float*)d_in[9];
    const float* b1  = (const float*)d_in[10];
    const float* gwi = (const float*)d_in[11];
    const float* gwh = (const float*)d_in[12];
    const float* gbi = (const float*)d_in[13];
    const float* gbh = (const float*)d_in[14];
    const float* q1w = (const float*)d_in[21];
    const float* qb1 = (const float*)d_in[22];
    const float* q2w = (const float*)d_in[23];
    const float* qb2 = (const float*)d_in[24];
    const float* wqm = (const float*)d_in[25];
    const float* bqm = (const float*)d_in[26];
    const float* wqs = (const float*)d_in[27];
    const float* bqs = (const float*)d_in[28];

    char* wsb = (char*)d_ws;
    size_t off = 0;
    auto alloc = [&](size_t bytes) {
        void* p = wsb + off;
        off = (off + bytes + 255) & ~(size_t)255;
        return p;
    };
    u16 *PW1[3], *PGI[3], *PGH[3], *PQ1[3], *PQ2[3], *PQH[3];
    for (int l = 0; l < 3; ++l) PW1[l] = (u16*)alloc((size_t)1280 * 1024 * 2);
    for (int l = 0; l < 3; ++l) PGI[l] = (u16*)alloc((size_t)1024 * 3072 * 2);
    for (int l = 0; l < 3; ++l) PGH[l] = (u16*)alloc((size_t)1024 * 3072 * 2);
    for (int l = 0; l < 3; ++l) PQ1[l] = (u16*)alloc((size_t)2048 * 1024 * 2);
    for (int l = 0; l < 3; ++l) PQ2[l] = (u16*)alloc((size_t)1024 * 1024 * 2);
    for (int l = 0; l < 3; ++l) PQH[l] = (u16*)alloc((size_t)1024 * 256 * 2);
    float* hbuf  = (float*)alloc((size_t)NB * NH * 4);
    float* hq1b  = (float*)alloc((size_t)NB * NH * 4);
    float* hq2b  = (float*)alloc((size_t)NB * NH * 4);
    float* detA  = (float*)alloc((size_t)NB * ND * 4);
    float* detB  = (float*)alloc((size_t)NB * ND * 4);
    float* samp  = (float*)alloc((size_t)NB * NS * 4);
    float* out1  = (float*)alloc((size_t)NB * 6 * NO * 4);
    float* out2  = (float*)alloc((size_t)NB * 1 * NO * 4);

    auto packW = [&](const float* src, int K, int N, u16* dst) {
        int total = (N >> 4) * (K >> 5) * 64;
        k_pack<<<dim3((total + 255) / 256), dim3(256), 0, stream>>>(src, K, N, dst);
    };
    for (int l = 0; l < 3; ++l) {
        packW(w1w + (size_t)l * 1280 * 1024, 1280, 1024, PW1[l]);
        packW(gwi + (size_t)l * 1024 * 3072, 1024, 3072, PGI[l]);
        packW(gwh + (size_t)l * 1024 * 3072, 1024, 3072, PGH[l]);
        packW(q1w + (size_t)l * 2048 * 1024, 2048, 1024, PQ1[l]);
        packW(q2w + (size_t)l * 1024 * 1024, 1024, 1024, PQ2[l]);
        packW(wqm + (size_t)l * 1024 * 128, 1024, 128, PQH[l]);
        packW(wqs + (size_t)l * 1024 * 128, 1024, 128, PQH[l] + (size_t)8 * 32 * 64 * 8);
    }

    const int Tarr[3] = {TT0, TT0 / FACT, TT0 / (FACT * FACT)};  // 36, 6, 1
    float* outbuf[3] = {(float*)d_out, out1, out2};

    for (int l = 2; l >= 0; --l) {
        int T = Tarr[l];
        hipMemsetAsync(samp, 0, (size_t)NB * NS * 4, stream);
        hipMemsetAsync(detA, 0, (size_t)NB * ND * 4, stream);
        float* dcur = detA;
        float* dnxt = detB;
        const float* outUp = (l == 2) ? nullptr : outbuf[l + 1];
        int Tup = (l == 2) ? 1 : Tarr[l + 1];
        for (int t = 0; t < T; ++t) {
            const float* ctx = outUp ? outUp + (size_t)(t / FACT) * NO : nullptr;
            // h = elu([sample, ctx] @ w1 + b1)
            k_dense<4, 36><<<16, 256, 0, stream>>>(samp, NS, ctx, Tup * NO,
                                                   (const bf16x8*)PW1[l], b1 + l * NH, hbuf);
            // GRU -> det_new
            k_gru<<<32, 256, 0, stream>>>(hbuf, dcur, (const bf16x8*)PGI[l],
                                          (const bf16x8*)PGH[l], gbi + (size_t)l * 3 * ND,
                                          gbh + (size_t)l * 3 * ND, dnxt);
            // hq1 = elu([det_new, obs] @ q1 + qb1)
            k_dense<32, 32><<<16, 256, 0, stream>>>(dnxt, ND, x[l] + (size_t)t * NE, T * NE,
                                                    (const bf16x8*)PQ1[l], qb1 + l * NH, hq1b);
            // hq2 = elu(hq1 @ q2 + qb2)
            k_dense<32, 0><<<16, 256, 0, stream>>>(hq1b, NH, nullptr, 0,
                                                   (const bf16x8*)PQ2[l], qb2 + l * NH, hq2b);
            // heads + out write
            k_out<<<18, 256, 0, stream>>>(hq2b, dnxt, (const bf16x8*)PQH[l], bqm + l * NS,
                                          bqs + l * NS, nqp[l] + (size_t)t * NS, T * NS, samp,
                                          outbuf[l] + (size_t)t * NO, T * NO);
            float* tmp = dcur; dcur = dnxt; dnxt = tmp;
        }
    }
}

// Round 2
// 2477.812 us; speedup vs baseline: 4.2473x; 4.2473x over previous
//
#include <hip/hip_runtime.h>
#include <hip/hip_bf16.h>
#include <math.h>

// CWVAE RSSM on MI355X, round 2.
// - Non-recurrent matmuls (ctx@w1_ctx, obs@q1_obs) hoisted out of the scan.
// - Per-step kernels: 64 blocks x 512 thr (4 m-tiles x 2-way K-split, LDS reduce).
// - Activations carried as bf16 row-major (A-fragment-ready, one 16B load/frag).
// - Single mega-pack kernel; GRU writes det slice of output directly; t==0 uses
//   null-pointer zero paths (no memsets).

#define LVLS 3
#define FACT 6
#define NB 64
#define TT0 36
#define NE 1024
#define NS 128
#define ND 1024
#define NH 1024
#define NO (NS + ND)  // 1152

typedef __attribute__((ext_vector_type(8))) short bf16x8;
typedef __attribute__((ext_vector_type(4))) float f32x4;
typedef unsigned short u16;

#define MFMA(a, b, c) __builtin_amdgcn_mfma_f32_16x16x32_bf16(a, b, c, 0, 0, 0)

__device__ inline u16 f2bf(float x) {
    unsigned u = __float_as_uint(x);
    unsigned r = u + 0x7fffu + ((u >> 16) & 1u);  // RNE
    return (u16)(r >> 16);
}

// ---------------------------------------------------------------------------
// Mega-pack: all 9 weight kinds x 3 levels, fp32 [K,N] -> bf16 frag layout
// frag-unit index f = nt*KT + kt ; frag(lane,e) = W[kt*32+(lane>>4)*8+e][nt*16+(lane&15)]
// Kinds: 0 W1S(128,1024) 1 W1C(1152,1024) 2 GWI(1024,3072) 3 GWH(1024,3072)
//        4 Q1D(1024,1024) 5 Q1O(1024,1024) 6 Q2(1024,1024) 7 WQM(1024,128) 8 WQS(1024,128)
__constant__ const int PFX[10] = {0, 256, 2560, 8704, 14848, 16896, 18944, 20992, 21248, 21504};
__constant__ const int KTS[9]  = {4, 36, 32, 32, 32, 32, 32, 32, 32};

__global__ __launch_bounds__(256) void k_pack_all(
    const float* __restrict__ w1, const float* __restrict__ gwi,
    const float* __restrict__ gwh, const float* __restrict__ q1,
    const float* __restrict__ q2, const float* __restrict__ wqm,
    const float* __restrict__ wqs, u16* __restrict__ dst) {
    int gid = blockIdx.x * 256 + threadIdx.x;
    int fu = gid >> 6, lane = gid & 63;
    int l = fu / 21504, f = fu % 21504;
    int kind = 0;
    while (f >= PFX[kind + 1]) ++kind;
    int local = f - PFX[kind];
    int KT = KTS[kind];
    int kt = local % KT, nt = local / KT;
    int k = kt * 32 + ((lane >> 4) << 3);
    int n = nt * 16 + (lane & 15);
    const float* src;
    int rw;
    switch (kind) {
        case 0: src = w1 + (size_t)l * 1310720 + (size_t)k * 1024 + n; rw = 1024; break;
        case 1: src = w1 + (size_t)l * 1310720 + (size_t)(128 + k) * 1024 + n; rw = 1024; break;
        case 2: src = gwi + (size_t)l * 3145728 + (size_t)k * 3072 + n; rw = 3072; break;
        case 3: src = gwh + (size_t)l * 3145728 + (size_t)k * 3072 + n; rw = 3072; break;
        case 4: src = q1 + (size_t)l * 2097152 + (size_t)k * 1024 + n; rw = 1024; break;
        case 5: src = q1 + (size_t)l * 2097152 + (size_t)(1024 + k) * 1024 + n; rw = 1024; break;
        case 6: src = q2 + (size_t)l * 1048576 + (size_t)k * 1024 + n; rw = 1024; break;
        case 7: src = wqm + (size_t)l * 131072 + (size_t)k * 128 + n; rw = 128; break;
        default: src = wqs + (size_t)l * 131072 + (size_t)k * 128 + n; rw = 128; break;
    }
    bf16x8 v;
#pragma unroll
    for (int e = 0; e < 8; ++e) v[e] = (short)f2bf(src[(size_t)e * rw]);
    reinterpret_cast<bf16x8*>(dst)[(size_t)fu * 64 + lane] = v;
}

// ---------------------------------------------------------------------------
// Precompute GEMM: A fp32 row-major [M][ldA] (convert on load), out fp32 [M][1024].
// Grid: x = nt (64), y = M/64 ; 256 thr (4 waves = m-tiles).
__global__ __launch_bounds__(256) void k_gemm_f32(
    const float* __restrict__ A, int ldA, int KT,
    const bf16x8* __restrict__ P, float* __restrict__ out) {
    int lane = threadIdx.x & 63, wave = threadIdx.x >> 6;
    int nt = blockIdx.x;
    int mt = blockIdx.y * 4 + wave;
    f32x4 acc = {};
    const float* a = A + (size_t)(mt * 16 + (lane & 15)) * ldA + ((lane >> 4) << 3);
    for (int kt = 0; kt < KT; ++kt) {
        float4 u0 = *(const float4*)(a + kt * 32);
        float4 u1 = *(const float4*)(a + kt * 32 + 4);
        bf16x8 fv;
        fv[0] = (short)f2bf(u0.x); fv[1] = (short)f2bf(u0.y);
        fv[2] = (short)f2bf(u0.z); fv[3] = (short)f2bf(u0.w);
        fv[4] = (short)f2bf(u1.x); fv[5] = (short)f2bf(u1.y);
        fv[6] = (short)f2bf(u1.z); fv[7] = (short)f2bf(u1.w);
        acc = MFMA(fv, P[((size_t)nt * KT + kt) * 64 + lane], acc);
    }
    int col = nt * 16 + (lane & 15);
    int row0 = mt * 16 + ((lane >> 4) << 2);
#pragma unroll
    for (int j = 0; j < 4; ++j) out[(size_t)(row0 + j) * 1024 + col] = acc[j];
}

// ---------------------------------------------------------------------------
// Per-step dense: out_bf16[64][ldO slice] = act(A_bf16[64][ldA] @ P + add + bias)
// Grid 64 x 512: wave = (m-tile & 3, khalf). A null -> zeros.
template <int KT, bool ELU>
__global__ __launch_bounds__(512) void k_denseX(
    const u16* __restrict__ A, int ldA, const bf16x8* __restrict__ P,
    const float* __restrict__ addp, int addStride, const float* __restrict__ bias,
    u16* __restrict__ outB, int ldO) {
    constexpr int KTH = KT / 2;
    __shared__ f32x4 red[4][64];
    __shared__ u16 ldsT[64][16];
    int tid = threadIdx.x, lane = tid & 63, wave = tid >> 6;
    int m = wave & 3, kh = wave >> 2;
    int nt = blockIdx.x;
    f32x4 acc = {};
    if (A) {
        const u16* a = A + (size_t)(m * 16 + (lane & 15)) * ldA + ((lane >> 4) << 3);
        for (int kt = kh * KTH; kt < kh * KTH + KTH; ++kt) {
            bf16x8 av = *(const bf16x8*)(a + kt * 32);
            acc = MFMA(av, P[((size_t)nt * KT + kt) * 64 + lane], acc);
        }
    }
    if (kh == 1) red[m][lane] = acc;
    __syncthreads();
    if (kh == 0) {
        acc += red[m][lane];
        int col = nt * 16 + (lane & 15);
        float bv = bias[col];
        int row0 = m * 16 + ((lane >> 4) << 2);
#pragma unroll
        for (int j = 0; j < 4; ++j) {
            int row = row0 + j;
            float x = acc[j] + bv;
            if (addp) x += addp[(size_t)row * addStride + col];
            if (ELU) x = x > 0.f ? x : expm1f(x);
            ldsT[row][lane & 15] = f2bf(x);
        }
    }
    __syncthreads();
    if (tid < 128) {
        int row = tid >> 1, seg = tid & 1;
        *(bf16x8*)(outB + (size_t)row * ldO + nt * 16 + seg * 8) =
            *(const bf16x8*)(&ldsT[row][seg * 8]);
    }
}

// ---------------------------------------------------------------------------
// Fused GRU. Grid 64 x 512. Writes det bf16 + fp32 and the det slice of out.
__global__ __launch_bounds__(512) void k_gru(
    const u16* __restrict__ hA, const u16* __restrict__ dA,
    const float* __restrict__ dF, const bf16x8* __restrict__ Pi,
    const bf16x8* __restrict__ Ph, const float* __restrict__ bi,
    const float* __restrict__ bh, u16* __restrict__ dA_out,
    float* __restrict__ dF_out, float* __restrict__ outp, int outStride) {
    __shared__ f32x4 red[4][6][64];
    __shared__ u16 ldsT[64][16];
    int tid = threadIdx.x, lane = tid & 63, wave = tid >> 6;
    int m = wave & 3, kh = wave >> 2;
    int nt = blockIdx.x;
    f32x4 acc[6] = {};  // ir iz in hr hz hn
    const u16* ah = hA + (size_t)(m * 16 + (lane & 15)) * 1024 + ((lane >> 4) << 3);
    const u16* ad = dA ? dA + (size_t)(m * 16 + (lane & 15)) * 1024 + ((lane >> 4) << 3) : nullptr;
    for (int kt = kh * 16; kt < kh * 16 + 16; ++kt) {
        bf16x8 av = *(const bf16x8*)(ah + kt * 32);
#pragma unroll
        for (int g = 0; g < 3; ++g)
            acc[g] = MFMA(av, Pi[((size_t)(g * 64 + nt) * 32 + kt) * 64 + lane], acc[g]);
        if (ad) {
            bf16x8 dv = *(const bf16x8*)(ad + kt * 32);
#pragma unroll
            for (int g = 0; g < 3; ++g)
                acc[3 + g] = MFMA(dv, Ph[((size_t)(g * 64 + nt) * 32 + kt) * 64 + lane], acc[3 + g]);
        }
    }
    if (kh == 1) {
#pragma unroll
        for (int q = 0; q < 6; ++q) red[m][q][lane] = acc[q];
    }
    __syncthreads();
    if (kh == 0) {
#pragma unroll
        for (int q = 0; q < 6; ++q) acc[q] += red[m][q][lane];
        int col = nt * 16 + (lane & 15);
        float bir = bi[col], biz = bi[1024 + col], bin = bi[2048 + col];
        float bhr = bh[col], bhz = bh[1024 + col], bhn = bh[2048 + col];
        int row0 = m * 16 + ((lane >> 4) << 2);
#pragma unroll
        for (int j = 0; j < 4; ++j) {
            int row = row0 + j;
            float r = 1.f / (1.f + expf(-(acc[0][j] + bir + acc[3][j] + bhr)));
            float z = 1.f / (1.f + expf(-(acc[1][j] + biz + acc[4][j] + bhz)));
            float n = tanhf(acc[2][j] + bin + r * (acc[5][j] + bhn));
            float dold = dF ? dF[(size_t)row * 1024 + col] : 0.f;
            float dn = (1.f - z) * n + z * dold;
            dF_out[(size_t)row * 1024 + col] = dn;
            outp[(size_t)row * outStride + 128 + col] = dn;
            ldsT[row][lane & 15] = f2bf(dn);
        }
    }
    __syncthreads();
    if (tid < 128) {
        int row = tid >> 1, seg = tid & 1;
        *(bf16x8*)(dA_out + (size_t)row * 1024 + nt * 16 + seg * 8) =
            *(const bf16x8*)(&ldsT[row][seg * 8]);
    }
}

// ---------------------------------------------------------------------------
// Heads: q = (hq2@wqm+bm) + (softplus(hq2@wqs+bs)+1e-4)*eps. Grid 8 x 512.
__global__ __launch_bounds__(512) void k_out(
    const u16* __restrict__ hA, const bf16x8* __restrict__ Pm,
    const bf16x8* __restrict__ Ps, const float* __restrict__ bm,
    const float* __restrict__ bs, const float* __restrict__ nq, int nqStride,
    u16* __restrict__ sampB, float* __restrict__ outp, int outStride) {
    __shared__ f32x4 red[4][2][64];
    __shared__ u16 ldsT[64][16];
    int tid = threadIdx.x, lane = tid & 63, wave = tid >> 6;
    int m = wave & 3, kh = wave >> 2;
    int nt = blockIdx.x;
    f32x4 am = {}, as_ = {};
    const u16* a = hA + (size_t)(m * 16 + (lane & 15)) * 1024 + ((lane >> 4) << 3);
    for (int kt = kh * 16; kt < kh * 16 + 16; ++kt) {
        bf16x8 av = *(const bf16x8*)(a + kt * 32);
        am = MFMA(av, Pm[((size_t)nt * 32 + kt) * 64 + lane], am);
        as_ = MFMA(av, Ps[((size_t)nt * 32 + kt) * 64 + lane], as_);
    }
    if (kh == 1) { red[m][0][lane] = am; red[m][1][lane] = as_; }
    __syncthreads();
    if (kh == 0) {
        am += red[m][0][lane];
        as_ += red[m][1][lane];
        int col = nt * 16 + (lane & 15);
        float bmv = bm[col], bsv = bs[col];
        int row0 = m * 16 + ((lane >> 4) << 2);
#pragma unroll
        for (int j = 0; j < 4; ++j) {
            int row = row0 + j;
            float mean = am[j] + bmv;
            float xs = as_[j] + bsv;
            float sp = fmaxf(xs, 0.f) + log1pf(expf(-fabsf(xs)));
            float q = mean + (sp + 1e-4f) * nq[(size_t)row * nqStride + col];
            outp[(size_t)row * outStride + col] = q;
            ldsT[row][lane & 15] = f2bf(q);
        }
    }
    __syncthreads();
    if (tid < 128) {
        int row = tid >> 1, seg = tid & 1;
        *(bf16x8*)(sampB + (size_t)row * 128 + nt * 16 + seg * 8) =
            *(const bf16x8*)(&ldsT[row][seg * 8]);
    }
}

// ---------------------------------------------------------------------------
extern "C" void kernel_launch(void* const* d_in, const int* in_sizes, int n_in,
                              void* d_out, int out_size, void* d_ws, size_t ws_size,
                              hipStream_t stream) {
    (void)n_in; (void)out_size; (void)ws_size;
    int ix[3], inq[3];
    if (in_sizes[1] == NB * TT0 * NS) {  // dict order
        ix[0] = 0; inq[0] = 2; ix[1] = 3; inq[1] = 5; ix[2] = 6; inq[2] = 8;
    } else {  // signature order
        ix[0] = 0; ix[1] = 1; ix[2] = 2; inq[0] = 6; inq[1] = 7; inq[2] = 8;
    }
    const float* x[3] = {(const float*)d_in[ix[0]], (const float*)d_in[ix[1]], (const float*)d_in[ix[2]]};
    const float* nqp[3] = {(const float*)d_in[inq[0]], (const float*)d_in[inq[1]], (const float*)d_in[inq[2]]};
    const float* w1w = (const float*)d_in[9];
    const float* b1  = (const float*)d_in[10];
    const float* gwi = (const float*)d_in[11];
    const float* gwh = (const float*)d_in[12];
    const float* gbi = (const float*)d_in[13];
    const float* gbh = (const float*)d_in[14];
    const float* q1w = (const float*)d_in[21];
    const float* qb1 = (const float*)d_in[22];
    const float* q2w = (const float*)d_in[23];
    const float* qb2 = (const float*)d_in[24];
    const float* wqm = (const float*)d_in[25];
    const float* bqm = (const float*)d_in[26];
    const float* wqs = (const float*)d_in[27];
    const float* bqs = (const float*)d_in[28];

    char* wsb = (char*)d_ws;
    size_t off = 0;
    auto alloc = [&](size_t bytes) {
        void* p = wsb + off;
        off = (off + bytes + 255) & ~(size_t)255;
        return p;
    };
    u16* wsW = (u16*)alloc((size_t)64512 * 1024);  // 66 MB packed weights
    const int Tarr[3] = {36, 6, 1};
    float* obs_pre[3];
    for (int l = 0; l < 3; ++l) obs_pre[l] = (float*)alloc((size_t)NB * Tarr[l] * 1024 * 4);
    float* c_pre[2];
    c_pre[0] = (float*)alloc((size_t)NB * 6 * 1024 * 4);
    c_pre[1] = (float*)alloc((size_t)NB * 1 * 1024 * 4);
    u16* hB   = (u16*)alloc((size_t)NB * 1024 * 2);
    u16* hq1B = (u16*)alloc((size_t)NB * 1024 * 2);
    u16* hq2B = (u16*)alloc((size_t)NB * 1024 * 2);
    u16* detB16[2] = {(u16*)alloc((size_t)NB * 1024 * 2), (u16*)alloc((size_t)NB * 1024 * 2)};
    float* detF[2] = {(float*)alloc((size_t)NB * 1024 * 4), (float*)alloc((size_t)NB * 1024 * 4)};
    u16* sampB = (u16*)alloc((size_t)NB * 128 * 2);
    float* out1 = (float*)alloc((size_t)NB * 6 * NO * 4);
    float* out2 = (float*)alloc((size_t)NB * 1 * NO * 4);

    const int pf[9] = {0, 256, 2560, 8704, 14848, 16896, 18944, 20992, 21248};
    auto Pk = [&](int l, int kind) -> const bf16x8* {
        return (const bf16x8*)wsW + ((size_t)l * 21504 + pf[kind]) * 64;
    };

    // 1. pack all weights (one launch)
    k_pack_all<<<16128, 256, 0, stream>>>(w1w, gwi, gwh, q1w, q2w, wqm, wqs, wsW);

    // 2. obs precompute for all levels: obs_pre[l] = x[l] @ Q1O[l]
    for (int l = 0; l < 3; ++l)
        k_gemm_f32<<<dim3(64, Tarr[l]), 256, 0, stream>>>(x[l], 1024, 32, Pk(l, 5), obs_pre[l]);

    float* outbuf[3] = {(float*)d_out, out1, out2};

    for (int l = 2; l >= 0; --l) {
        int T = Tarr[l];
        if (l < 2) {  // ctx precompute: c_pre[l] = outbuf[l+1] @ W1C[l]
            int Tup = Tarr[l + 1];
            k_gemm_f32<<<dim3(64, Tup), 256, 0, stream>>>(outbuf[l + 1], 1152, 36, Pk(l, 1),
                                                          c_pre[l]);
        }
        int Tup = (l == 2) ? 1 : Tarr[l + 1];
        int cur = 1;
        for (int t = 0; t < T; ++t) {
            const u16* sampA = t ? sampB : nullptr;
            const u16* dIn16 = t ? detB16[cur] : nullptr;
            const float* dInF = t ? detF[cur] : nullptr;
            u16* dOut16 = detB16[cur ^ 1];
            float* dOutF = detF[cur ^ 1];
            const float* addw1 = (l == 2) ? nullptr : c_pre[l] + (size_t)(t / FACT) * 1024;
            float* outp = outbuf[l] + (size_t)t * NO;

            k_denseX<4, true><<<64, 512, 0, stream>>>(sampA, 128, Pk(l, 0), addw1, Tup * 1024,
                                                      b1 + l * 1024, hB, 1024);
            k_gru<<<64, 512, 0, stream>>>(hB, dIn16, dInF, Pk(l, 2), Pk(l, 3),
                                          gbi + (size_t)l * 3072, gbh + (size_t)l * 3072, dOut16,
                                          dOutF, outp, T * NO);
            k_denseX<32, true><<<64, 512, 0, stream>>>(dOut16, 1024, Pk(l, 4),
                                                       obs_pre[l] + (size_t)t * 1024, T * 1024,
                                                       qb1 + l * 1024, hq1B, 1024);
            k_denseX<32, true><<<64, 512, 0, stream>>>(hq1B, 1024, Pk(l, 6), nullptr, 0,
                                                       qb2 + l * 1024, hq2B, 1024);
            k_out<<<8, 512, 0, stream>>>(hq2B, Pk(l, 7), Pk(l, 8), bqm + l * 128, bqs + l * 128,
                                         nqp[l] + (size_t)t * 128, T * 128, sampB, outp, T * NO);
            cur ^= 1;
        }
    }
}